// Round 17
// baseline (186.232 us; speedup 1.0000x reference)
//
#include <hip/hip_runtime.h>
#include <cstdint>

// Problem constants (from reference)
constexpr int B_   = 4096;
constexpr int T_   = 512;
constexpr int DIN  = 10;
constexpr int H_   = 20;
constexpr int DOUT = 2;

typedef float    v2f  __attribute__((ext_vector_type(2)));
typedef float    v4f  __attribute__((ext_vector_type(4)));
typedef int      v4i  __attribute__((ext_vector_type(4)));
typedef _Float16 h2t  __attribute__((ext_vector_type(2)));
typedef __fp16   fp2t __attribute__((ext_vector_type(2)));

constexpr float SCL = 2.885390082f;   // 2*log2(e), folded into weights/biases

#define CFENCE() asm volatile("" ::: "memory")

__device__ __forceinline__ v2f pkfma(v2f a, v2f b, v2f c) {
    return __builtin_elementwise_fma(a, b, c);
}

// v_dot2_f32_f16: D = a.x*b.x + a.y*b.y + c (f32 accumulate, one instr)
__device__ __forceinline__ float fdot2(h2t a, h2t b, float c) {
#if __has_builtin(__builtin_amdgcn_fdot2)
    return __builtin_amdgcn_fdot2(a, b, c, false);
#else
    return fmaf((float)a.x, (float)b.x, fmaf((float)a.y, (float)b.y, c));
#endif
}

// tanh from PRE-SCALED input s = 2*log2e*v: 4-op chain, exact saturation
__device__ __forceinline__ float tanh_pre(float s) {
    float e = __builtin_amdgcn_exp2f(s);
    float r = __builtin_amdgcn_rcpf(e + 1.0f);
    return fmaf(-2.0f, r, 1.0f);
}

union HI { int i; h2t h; fp2t f; };

// 16 lanes per sample (4 samples/wave, 1024 waves = 1/SIMD).
// Lane m owns outputs j1=m and (m<4) j2=16+m.
// State pair (h1[j],h2[j]) packed as one f16x2 dword:
//   - j=0..15  : all-gathered across the row via 15 v_mov_dpp ROW_ROR ops
//                (VALU crossbar -- ZERO DS-pipe ops on the recurrent chain;
//                 R10..R16 established each DS op costs ~38cyc on the chain)
//   - j=16..19 : 1 ds_write_b32 + 1 ds_read_b128 side channel, consumed one
//                full step later (latency off-chain)
// Skewed recurrence (R13 semantics): per step compute h1(tau) [L0] and
// h2(tau-1) [L1]; both read only committed register state.
// Weight order is SELF-CALIBRATED: init probes the DPP rotation's actual
// source lane by rotating lane-ids, then gathers weights in that order.
extern "C" __global__ void __launch_bounds__(64, 1)
rnn_dpp(const float* __restrict__ x,
        const float* __restrict__ w_ih0, const float* __restrict__ w_hh0,
        const float* __restrict__ b_ih0, const float* __restrict__ b_hh0,
        const float* __restrict__ w_ih1, const float* __restrict__ w_hh1,
        const float* __restrict__ b_ih1, const float* __restrict__ b_hh1,
        const float* __restrict__ fc_w, const float* __restrict__ fc_b,
        float* __restrict__ out)
{
    const int lane = threadIdx.x;
    const int row  = lane >> 4;          // sample slot 0..3
    const int m    = lane & 15;          // row-lane
    const int samp = blockIdx.x * 4 + row;     // grid=1024 -> always < B_
    const float msk2 = (m < 4) ? 1.0f : 0.0f;  // second-output validity
    const int   j1 = m;
    const int   j2 = (m < 4) ? (16 + m) : 19;  // clamped for safe loads

    __shared__ int   ldsB[4][16];        // side channel (outputs 16..19)
    __shared__ float ldsF[4][20];        // epilogue FC buffer

    // ---- probe actual DPP ROW_ROR source indices (self-calibrating) ----
    int dsrc[16];
    dsrc[0] = m;
#define PROBE(R) dsrc[R] = __builtin_amdgcn_mov_dpp(m, 0x120 + R, 0xf, 0xf, true);
    PROBE(1) PROBE(2) PROBE(3) PROBE(4) PROBE(5) PROBE(6) PROBE(7) PROBE(8)
    PROBE(9) PROBE(10) PROBE(11) PROBE(12) PROBE(13) PROBE(14) PROBE(15)
#undef PROBE

    // ---- weights in rotation-delivery order, f16 pairs, pre-scaled ----
    // A-path pairs multiply state (h1[d], h2[d]):
    //   L0 wants h1 only -> (wh0, 0); L1 wants both -> (wi1, wh1)
    h2t w0A[2][16], w1A[2][16], w0B[2][4], w1B[2][4];
    v2f wx[2][5];
    float bx[2], b1v[2];
    #pragma unroll
    for (int o = 0; o < 2; ++o) {
        const int   j  = o ? j2 : j1;
        const float mk = o ? msk2 : 1.0f;
        #pragma unroll
        for (int r = 0; r < 16; ++r) {
            const int d = dsrc[r];
            w0A[o][r] = h2t{(_Float16)(SCL * mk * w_hh0[j * H_ + d]), (_Float16)0.f};
            w1A[o][r] = h2t{(_Float16)(SCL * mk * w_ih1[j * H_ + d]),
                            (_Float16)(SCL * mk * w_hh1[j * H_ + d])};
        }
        #pragma unroll
        for (int d = 0; d < 4; ++d) {
            w0B[o][d] = h2t{(_Float16)(SCL * mk * w_hh0[j * H_ + 16 + d]), (_Float16)0.f};
            w1B[o][d] = h2t{(_Float16)(SCL * mk * w_ih1[j * H_ + 16 + d]),
                            (_Float16)(SCL * mk * w_hh1[j * H_ + 16 + d])};
        }
        #pragma unroll
        for (int q = 0; q < 5; ++q) {
            wx[o][q] = (v2f){SCL * mk * w_ih0[j * DIN + 2 * q],
                             SCL * mk * w_ih0[j * DIN + 2 * q + 1]};
        }
        bx[o]  = SCL * mk * (b_ih0[j] + b_hh0[j]);
        b1v[o] = SCL * mk * (b_ih1[j] + b_hh1[j]);
    }

    // ---- state: sA[r] = (h1[dsrc[r]], h2[dsrc[r]]), sB[d] = outputs 16+d ----
    h2t sA[16], sB[4];
    #pragma unroll
    for (int r = 0; r < 16; ++r) sA[r] = h2t{(_Float16)0.f, (_Float16)0.f};
    #pragma unroll
    for (int d = 0; d < 4; ++d)  sB[d] = h2t{(_Float16)0.f, (_Float16)0.f};

    const float* xr = x + (size_t)samp * (T_ * DIN);
    v2f xc[5], xn[5];    // double-buffered x rows (8B-aligned v2f loads)
    #pragma unroll
    for (int q = 0; q < 5; ++q) {
        xc[q] = reinterpret_cast<const v2f*>(xr)[q];
        xn[q] = reinterpret_cast<const v2f*>(xr + DIN)[q];
    }
    auto refill = [&](v2f (&buf)[5], int t) {
        const v2f* p = reinterpret_cast<const v2f*>(xr + (size_t)t * DIN);
        #pragma unroll
        for (int q = 0; q < 5; ++q) buf[q] = p[q];
    };
    auto xproj = [&](const v2f (&buf)[5], float (&xp)[2]) {
        #pragma unroll
        for (int o = 0; o < 2; ++o) {
            v2f a = (v2f){bx[o], 0.f};
            #pragma unroll
            for (int q = 0; q < 5; ++q) a = pkfma(buf[q], wx[o][q], a);
            xp[o] = a.x + a.y;
        }
    };

    // one skewed step; keep=0 kills the (undefined) L1 output at tau=0
    auto full_step = [&](float xp0, float xp1, float keep) {
        // ---- L0: h1n[j_o] = tanh(xp_o + wh0[j_o] . h1) ----
        float h1n0, h1n1;
        {
            float p0 = xp0, p1 = 0.f, p2 = 0.f, p3 = 0.f;
            #pragma unroll
            for (int r = 0; r < 16; r += 4) {
                p0 = fdot2(sA[r + 0], w0A[0][r + 0], p0);
                p1 = fdot2(sA[r + 1], w0A[0][r + 1], p1);
                p2 = fdot2(sA[r + 2], w0A[0][r + 2], p2);
                p3 = fdot2(sA[r + 3], w0A[0][r + 3], p3);
            }
            p0 = fdot2(sB[0], w0B[0][0], p0);
            p1 = fdot2(sB[1], w0B[0][1], p1);
            p2 = fdot2(sB[2], w0B[0][2], p2);
            p3 = fdot2(sB[3], w0B[0][3], p3);
            h1n0 = tanh_pre((p0 + p1) + (p2 + p3));
        }
        {
            float p0 = xp1, p1 = 0.f, p2 = 0.f, p3 = 0.f;
            #pragma unroll
            for (int r = 0; r < 16; r += 4) {
                p0 = fdot2(sA[r + 0], w0A[1][r + 0], p0);
                p1 = fdot2(sA[r + 1], w0A[1][r + 1], p1);
                p2 = fdot2(sA[r + 2], w0A[1][r + 2], p2);
                p3 = fdot2(sA[r + 3], w0A[1][r + 3], p3);
            }
            p0 = fdot2(sB[0], w0B[1][0], p0);
            p1 = fdot2(sB[1], w0B[1][1], p1);
            p2 = fdot2(sB[2], w0B[1][2], p2);
            p3 = fdot2(sB[3], w0B[1][3], p3);
            h1n1 = tanh_pre((p0 + p1) + (p2 + p3));
        }
        // ---- L1 (skewed): h2n[j_o] = tanh(b1 + wi1.h1 + wh1.h2) ----
        float h2n0, h2n1;
        {
            float q0 = b1v[0], q1 = 0.f, q2 = 0.f, q3 = 0.f;
            #pragma unroll
            for (int r = 0; r < 16; r += 4) {
                q0 = fdot2(sA[r + 0], w1A[0][r + 0], q0);
                q1 = fdot2(sA[r + 1], w1A[0][r + 1], q1);
                q2 = fdot2(sA[r + 2], w1A[0][r + 2], q2);
                q3 = fdot2(sA[r + 3], w1A[0][r + 3], q3);
            }
            q0 = fdot2(sB[0], w1B[0][0], q0);
            q1 = fdot2(sB[1], w1B[0][1], q1);
            q2 = fdot2(sB[2], w1B[0][2], q2);
            q3 = fdot2(sB[3], w1B[0][3], q3);
            h2n0 = keep * tanh_pre((q0 + q1) + (q2 + q3));
        }
        {
            float q0 = b1v[1], q1 = 0.f, q2 = 0.f, q3 = 0.f;
            #pragma unroll
            for (int r = 0; r < 16; r += 4) {
                q0 = fdot2(sA[r + 0], w1A[1][r + 0], q0);
                q1 = fdot2(sA[r + 1], w1A[1][r + 1], q1);
                q2 = fdot2(sA[r + 2], w1A[1][r + 2], q2);
                q3 = fdot2(sA[r + 3], w1A[1][r + 3], q3);
            }
            q0 = fdot2(sB[0], w1B[1][0], q0);
            q1 = fdot2(sB[1], w1B[1][1], q1);
            q2 = fdot2(sB[2], w1B[1][2], q2);
            q3 = fdot2(sB[3], w1B[1][3], q3);
            h2n1 = keep * tanh_pre((q0 + q1) + (q2 + q3));
        }

        // ---- pack & exchange ----
        HI A; A.f = __builtin_amdgcn_cvt_pkrtz(h1n0, h2n0);
        h2t nA[16];
        nA[0] = A.h;
#define GATH(R) { HI t_; t_.i = __builtin_amdgcn_mov_dpp(A.i, 0x120 + R, 0xf, 0xf, true); nA[R] = t_.h; }
        GATH(1) GATH(2) GATH(3) GATH(4) GATH(5) GATH(6) GATH(7) GATH(8)
        GATH(9) GATH(10) GATH(11) GATH(12) GATH(13) GATH(14) GATH(15)
#undef GATH
        HI Bv; Bv.f = __builtin_amdgcn_cvt_pkrtz(h1n1, h2n1);
        CFENCE();
        ldsB[row][m] = Bv.i;             // unique address per lane, no branch
        v4i rb = *reinterpret_cast<const v4i*>(&ldsB[row][0]);   // cols 0..3
        CFENCE();
        #pragma unroll
        for (int r = 0; r < 16; ++r) sA[r] = nA[r];
        #pragma unroll
        for (int d = 0; d < 4; ++d) { HI t_; t_.i = rb[d]; sB[d] = t_.h; }
    };

    // ---- tau = 0 (peel: keep=0 -> h2 state stays 0) ----
    float xp[2], xp2[2];
    xproj(xc, xp);
    full_step(xp[0], xp[1], 0.0f);
    refill(xc, 2);

    // ---- tau = 1..510 in pairs; xn=odd rows, xc=even rows ----
    for (int t = 1; t <= 509; t += 2) {
        xproj(xn, xp);
        full_step(xp[0], xp[1], 1.0f);       // tau = t
        refill(xn, (t + 2 <= 511) ? (t + 2) : 511);
        xproj(xc, xp2);
        full_step(xp2[0], xp2[1], 1.0f);     // tau = t+1
        refill(xc, (t + 3 <= 511) ? (t + 3) : 511);
    }
    // ---- tau = 511 (xn holds row 511) ----
    xproj(xn, xp);
    full_step(xp[0], xp[1], 1.0f);

    // ---- epilogue: h2(511) from sA=(h1(511),h2(510)), sB ----
    float h2f0, h2f1;
    {
        float q0 = b1v[0], q1 = 0.f, q2 = 0.f, q3 = 0.f;
        #pragma unroll
        for (int r = 0; r < 16; r += 4) {
            q0 = fdot2(sA[r + 0], w1A[0][r + 0], q0);
            q1 = fdot2(sA[r + 1], w1A[0][r + 1], q1);
            q2 = fdot2(sA[r + 2], w1A[0][r + 2], q2);
            q3 = fdot2(sA[r + 3], w1A[0][r + 3], q3);
        }
        q0 = fdot2(sB[0], w1B[0][0], q0);
        q1 = fdot2(sB[1], w1B[0][1], q1);
        q2 = fdot2(sB[2], w1B[0][2], q2);
        q3 = fdot2(sB[3], w1B[0][3], q3);
        h2f0 = tanh_pre((q0 + q1) + (q2 + q3));
    }
    {
        float q0 = b1v[1], q1 = 0.f, q2 = 0.f, q3 = 0.f;
        #pragma unroll
        for (int r = 0; r < 16; r += 4) {
            q0 = fdot2(sA[r + 0], w1A[1][r + 0], q0);
            q1 = fdot2(sA[r + 1], w1A[1][r + 1], q1);
            q2 = fdot2(sA[r + 2], w1A[1][r + 2], q2);
            q3 = fdot2(sA[r + 3], w1A[1][r + 3], q3);
        }
        q0 = fdot2(sB[0], w1B[1][0], q0);
        q1 = fdot2(sB[1], w1B[1][1], q1);
        q2 = fdot2(sB[2], w1B[1][2], q2);
        q3 = fdot2(sB[3], w1B[1][3], q3);
        h2f1 = tanh_pre((q0 + q1) + (q2 + q3));
    }
    CFENCE();
    ldsF[row][m] = h2f0;
    if (m < 4) ldsF[row][16 + m] = h2f1;
    CFENCE();

    // ---- FC: lanes m<2 emit out[samp][m] ----
    if (m < DOUT) {
        float acc = fc_b[m];
        #pragma unroll
        for (int j = 0; j < H_; ++j) acc = fmaf(ldsF[row][j], fc_w[m * H_ + j], acc);
        out[samp * DOUT + m] = acc;
    }
}

extern "C" void kernel_launch(void* const* d_in, const int* in_sizes, int n_in,
                              void* d_out, int out_size, void* d_ws, size_t ws_size,
                              hipStream_t stream) {
    (void)in_sizes; (void)n_in; (void)d_ws; (void)ws_size; (void)out_size;
    const float* x     = (const float*)d_in[0];
    const float* w_ih0 = (const float*)d_in[1];
    const float* w_hh0 = (const float*)d_in[2];
    const float* b_ih0 = (const float*)d_in[3];
    const float* b_hh0 = (const float*)d_in[4];
    const float* w_ih1 = (const float*)d_in[5];
    const float* w_hh1 = (const float*)d_in[6];
    const float* b_ih1 = (const float*)d_in[7];
    const float* b_hh1 = (const float*)d_in[8];
    const float* fc_w  = (const float*)d_in[9];
    const float* fc_b  = (const float*)d_in[10];
    float* out = (float*)d_out;

    hipLaunchKernelGGL(rnn_dpp, dim3(B_ / 4), dim3(64), 0, stream,
                       x, w_ih0, w_hh0, b_ih0, b_hh0,
                       w_ih1, w_hh1, b_ih1, b_hh1, fc_w, fc_b, out);
}